// Round 15
// baseline (134.365 us; speedup 1.0000x reference)
//
#include <hip/hip_runtime.h>
#include <hip/hip_bf16.h>

typedef __attribute__((ext_vector_type(8)))  short short8;
typedef __attribute__((ext_vector_type(16))) float f32x16;
typedef _Float16 __attribute__((ext_vector_type(8))) half8;

#define DIM   64
#define K_CL  512
#define N_PTS 524288
#define OUTSZ (K_CL * DIM + K_CL)   // 33280

// pack two fp32 -> one u32 of 2x bf16 (RNE) via compiler cvt_pk path
__device__ inline unsigned int pk_bf16(float a, float b) {
    float2 t; t.x = a; t.y = b;
    __hip_bfloat162 h2 = __float22bfloat162_rn(t);
    unsigned int u;
    __builtin_memcpy(&u, &h2, 4);
    return u;
}

// convert float4 -> 4 fp16 (RNE via v_cvt_f16_f32), packed as uint2
__device__ inline uint2 cvt4_f16(const float4& v) {
    unsigned short a = __builtin_bit_cast(unsigned short, (_Float16)v.x);
    unsigned short b = __builtin_bit_cast(unsigned short, (_Float16)v.y);
    unsigned short c = __builtin_bit_cast(unsigned short, (_Float16)v.z);
    unsigned short d = __builtin_bit_cast(unsigned short, (_Float16)v.w);
    uint2 w;
    w.x = (unsigned int)a | ((unsigned int)b << 16);
    w.y = (unsigned int)c | ((unsigned int)d << 16);
    return w;
}

// ---------------------------------------------------------------------------
// prep: one 64-lane block per center. hc2 = 0.5*||c||^2 (shuffle reduce);
// chi = fp16 of NEGATED center (single plane; fp16 1-product assign).
// ---------------------------------------------------------------------------
__global__ __launch_bounds__(64)
void prep_kernel(const float* __restrict__ c,
                 unsigned short* __restrict__ chi,
                 float* __restrict__ hc2) {
    const int k = blockIdx.x, d = threadIdx.x;
    float v = c[k * DIM + d];
    float s = v * v;
#pragma unroll
    for (int off = 1; off < 64; off <<= 1) s += __shfl_xor(s, off, 64);

    chi[k * DIM + d] = __builtin_bit_cast(unsigned short, (_Float16)(-v));
    if (d == 0) hc2[k] = 0.5f * s;
}

// ---------------------------------------------------------------------------
// assign v4 (unchanged from round 14): fp16 single-product, 1024 blocks x
// 512 thr, 16 tiles; bias as ks=0 MFMA C-in; double-buffered staging; one
// barrier per tile; exact float argmin; u64 atomicMin winner.
// ---------------------------------------------------------------------------
__global__ __launch_bounds__(512, 4)
void assign_kernel(const float* __restrict__ x,
                   const unsigned short* __restrict__ chi_g,
                   const float* __restrict__ hc2g,
                   unsigned int* __restrict__ assign) {
    __shared__ unsigned int lds_x[2][1024];
    __shared__ float lds_bias[512];
    __shared__ unsigned long long lds_best[512];

    const int tid  = threadIdx.x;
    const int wave = tid >> 6;
    const int lane = tid & 63;
    const int l31  = lane & 31;
    const int h    = lane >> 5;

    lds_best[tid] = ~0ull;
    {
        int w = tid >> 6, ct = (tid >> 5) & 1, hh = (tid >> 4) & 1, r = tid & 15;
        lds_bias[tid] = hc2g[w * 64 + ct * 32 + (r & 3) + 8 * (r >> 2) + 4 * hh];
    }

    half8 cH[2][4];
#pragma unroll
    for (int ct = 0; ct < 2; ++ct) {
        int row = wave * 64 + ct * 32 + l31;
#pragma unroll
        for (int ks = 0; ks < 4; ++ks) {
            size_t off = (size_t)row * DIM + ks * 16 + h * 8;
            cH[ct][ks] = __builtin_bit_cast(half8, *(const short8*)(chi_g + off));
        }
    }

    const int p_st  = tid >> 4;
    const int dgrp  = tid & 15;
    const int f_st  = dgrp >> 1;
    const int half  = dgrp & 1;
    const int widx  = f_st * 128 + ((p_st ^ (f_st & 7)) << 2) + half * 2;

    const size_t xbase = (size_t)blockIdx.x * 32768 + tid * 4;

#define STAGE(buf, v4)                                                        \
    {                                                                         \
        uint2 w2 = cvt4_f16(v4);                                              \
        *(uint2*)&lds_x[buf][widx] = w2;                                      \
    }

    float4 pf = *(const float4*)(x + xbase);
    STAGE(0, pf)
    pf = *(const float4*)(x + xbase + 2048);
    __syncthreads();

    f32x16 bias0, bias1;
    {
        const float4* b0 = (const float4*)&lds_bias[wave * 64 + h * 16];
        const float4* b1 = (const float4*)&lds_bias[wave * 64 + 32 + h * 16];
#pragma unroll
        for (int g = 0; g < 4; ++g) {
            float4 a = b0[g], bb = b1[g];
            bias0[4*g+0] = a.x;  bias0[4*g+1] = a.y;  bias0[4*g+2] = a.z;  bias0[4*g+3] = a.w;
            bias1[4*g+0] = bb.x; bias1[4*g+1] = bb.y; bias1[4*g+2] = bb.z; bias1[4*g+3] = bb.w;
        }
    }

    const unsigned int base_id = wave * 64 + 4 * h;

    for (int t = 0; t < 16; ++t) {
        const int b = t & 1;
        if (t < 15) STAGE(b ^ 1, pf)
        if (t < 14) pf = *(const float4*)(x + xbase + (size_t)(t + 2) * 2048);

        f32x16 acc0, acc1;
        {
            const int ridx = h * 128 + ((l31 ^ (h & 7)) << 2);
            half8 xh = __builtin_bit_cast(half8, *(const short8*)&lds_x[b][ridx]);
            acc0 = __builtin_amdgcn_mfma_f32_32x32x16_f16(cH[0][0], xh, bias0, 0, 0, 0);
            acc1 = __builtin_amdgcn_mfma_f32_32x32x16_f16(cH[1][0], xh, bias1, 0, 0, 0);
        }
#pragma unroll
        for (int ks = 1; ks < 4; ++ks) {
            const int f = ks * 2 + h;
            const int ridx = f * 128 + ((l31 ^ (f & 7)) << 2);
            half8 xh = __builtin_bit_cast(half8, *(const short8*)&lds_x[b][ridx]);
            acc0 = __builtin_amdgcn_mfma_f32_32x32x16_f16(cH[0][ks], xh, acc0, 0, 0, 0);
            acc1 = __builtin_amdgcn_mfma_f32_32x32x16_f16(cH[1][ks], xh, acc1, 0, 0, 0);
        }

        float bv = acc0[0];
        unsigned int boff = 0;
#pragma unroll
        for (int r = 1; r < 16; ++r) {
            unsigned int off = (r & 3) + 8 * (r >> 2);
            if (acc0[r] < bv) { bv = acc0[r]; boff = off; }
        }
#pragma unroll
        for (int r = 0; r < 16; ++r) {
            unsigned int off = 32 + (r & 3) + 8 * (r >> 2);
            if (acc1[r] < bv) { bv = acc1[r]; boff = off; }
        }

        unsigned int ub = __builtin_bit_cast(unsigned int, bv);
        ub ^= (unsigned int)(((int)ub) >> 31) | 0x80000000u;
        unsigned long long pk =
            ((unsigned long long)ub << 32) | (unsigned long long)(base_id + boff);
        atomicMin(&lds_best[t * 32 + l31], pk);
        __syncthreads();
    }
#undef STAGE

    assign[blockIdx.x * 512 + tid] = (unsigned int)(lds_best[tid] & 0xFFFFFFFFu);
}

// ---------------------------------------------------------------------------
// reduce v6: one-hot MFMA, bf16-hi B operand; slab or atomic flush.
// CHANGED: single barrier per superchunk (reads hit buf[b], writes hit
// buf[b^1] -- disjoint between barriers, assign-kernel pattern). Grid is
// now adaptive (P=1024 -> nsc=4 for 32 waves/CU, or P=512 -> nsc=8).
// ---------------------------------------------------------------------------
template <int SLAB>
__global__ __launch_bounds__(512)
void reduce_kernel(const float* __restrict__ x,
                   const unsigned int* __restrict__ assign,
                   float* __restrict__ gsums, float* __restrict__ gcnt,
                   unsigned int* __restrict__ slab_u32,
                   float* __restrict__ cnt_slab, int nsc) {
    __shared__ unsigned short lds_h[2][64][128];
    __shared__ unsigned int   lds_a[2][128];
    __shared__ float          lds_cnt[K_CL];

    const int tid  = threadIdx.x;
    const int wave = tid >> 6;
    const int lane = tid & 63;
    const int l31  = lane & 31;
    const int h    = lane >> 5;
    const int d    = lane;
    const int pg   = wave;

    lds_cnt[tid] = 0.f;

    const size_t pbase = (size_t)blockIdx.x * (size_t)(nsc * 128);

    float f[16];
    {
        const float* xp = x + (pbase + pg * 16) * DIM + d;
#pragma unroll
        for (int i = 0; i < 16; ++i) f[i] = xp[(size_t)i * DIM];
    }
    __syncthreads();   // lds_cnt zeros visible

    for (int i = 0; i < (nsc >> 2); ++i)
        atomicAdd(&lds_cnt[assign[pbase + tid + i * 512]], 1.f);

    const int swz = (d & 15) << 3;

#define WRITE_BUF(b)                                                          \
    {                                                                         \
        unsigned int hw[8];                                                   \
        _Pragma("unroll")                                                     \
        for (int q = 0; q < 8; ++q) hw[q] = pk_bf16(f[2*q], f[2*q+1]);        \
        unsigned short* rh = &lds_h[b][d][0];                                 \
        const int j0 = (pg * 16) ^ swz;                                       \
        const int j1 = (pg * 16 + 8) ^ swz;                                   \
        uint4 u;                                                              \
        u.x=hw[0]; u.y=hw[1]; u.z=hw[2]; u.w=hw[3]; *(uint4*)&rh[j0] = u;     \
        u.x=hw[4]; u.y=hw[5]; u.z=hw[6]; u.w=hw[7]; *(uint4*)&rh[j1] = u;     \
    }

    WRITE_BUF(0)
    if (tid < 32) {
        uint4 av = *(const uint4*)(assign + pbase + tid * 4);
        *(uint4*)&lds_a[0][tid * 4] = av;
    }
    __syncthreads();

    const unsigned int row0 = wave * 64 + l31;
    const unsigned int row1 = row0 + 32;
    f32x16 C00 = {}, C01 = {}, C10 = {}, C11 = {};

    for (int sc = 0; sc < nsc; ++sc) {
        const int b = sc & 1;
        if (sc < nsc - 1) {   // issue next superchunk's loads under compute
            const float* xp = x + (pbase + (size_t)(sc + 1) * 128 + pg * 16) * DIM + d;
#pragma unroll
            for (int i = 0; i < 16; ++i) f[i] = xp[(size_t)i * DIM];
        }

#pragma unroll
        for (int c = 0; c < 8; ++c) {
            const unsigned int* ap = &lds_a[b][c * 16 + 8 * h];
            uint4 aA = *(const uint4*)ap;
            uint4 aB = *(const uint4*)(ap + 4);
            unsigned int a[8] = {aA.x, aA.y, aA.z, aA.w, aB.x, aB.y, aB.z, aB.w};
            unsigned int i0[4], i1[4];
#pragma unroll
            for (int q = 0; q < 4; ++q) {
                i0[q] = (a[2*q]==row0 ? 0x3F80u : 0u) | (a[2*q+1]==row0 ? 0x3F800000u : 0u);
                i1[q] = (a[2*q]==row1 ? 0x3F80u : 0u) | (a[2*q+1]==row1 ? 0x3F800000u : 0u);
            }
            uint4 u0; u0.x=i0[0]; u0.y=i0[1]; u0.z=i0[2]; u0.w=i0[3];
            uint4 u1; u1.x=i1[0]; u1.y=i1[1]; u1.z=i1[2]; u1.w=i1[3];
            short8 A0 = __builtin_bit_cast(short8, u0);
            short8 A1 = __builtin_bit_cast(short8, u1);

            const int off = (c * 16 + 8 * h) ^ ((l31 & 15) << 3);
            short8 xh0 = *(const short8*)&lds_h[b][l31][off];
            short8 xh1 = *(const short8*)&lds_h[b][l31 + 32][off];

            C00 = __builtin_amdgcn_mfma_f32_32x32x16_bf16(A0, xh0, C00, 0, 0, 0);
            C01 = __builtin_amdgcn_mfma_f32_32x32x16_bf16(A0, xh1, C01, 0, 0, 0);
            C10 = __builtin_amdgcn_mfma_f32_32x32x16_bf16(A1, xh0, C10, 0, 0, 0);
            C11 = __builtin_amdgcn_mfma_f32_32x32x16_bf16(A1, xh1, C11, 0, 0, 0);
        }

        if (sc < nsc - 1) {   // write NEXT buffer (disjoint from reads of b)
            WRITE_BUF(b ^ 1)
            if (tid < 32) {
                uint4 av = *(const uint4*)(assign + pbase + (size_t)(sc + 1) * 128 + tid * 4);
                *(uint4*)&lds_a[b ^ 1][tid * 4] = av;
            }
        }
        __syncthreads();   // single barrier per superchunk
    }
#undef WRITE_BUF

    if (SLAB) {
        cnt_slab[blockIdx.x * K_CL + tid] = lds_cnt[tid];
        unsigned int* myslab = slab_u32 + (size_t)blockIdx.x * 16384;
#pragma unroll
        for (int r = 0; r < 16; ++r) {
            int ro = (r & 3) + 8 * (r >> 2) + 4 * h;
            int k0 = wave * 64 + ro;
            myslab[k0 * 32 + l31]        = pk_bf16(C00[r], C01[r]);
            myslab[(k0 + 32) * 32 + l31] = pk_bf16(C10[r], C11[r]);
        }
    } else {
        atomicAdd(&gcnt[tid], lds_cnt[tid]);
#pragma unroll
        for (int rr = 0; rr < 16; ++rr) {
            int r = (rr + (int)(blockIdx.x & 15)) & 15;
            int ro = (r & 3) + 8 * (r >> 2) + 4 * h;
            atomicAdd(&gsums[(wave * 64 + ro) * DIM + l31],           C00[r]);
            atomicAdd(&gsums[(wave * 64 + ro) * DIM + 32 + l31],      C01[r]);
            atomicAdd(&gsums[(wave * 64 + 32 + ro) * DIM + l31],      C10[r]);
            atomicAdd(&gsums[(wave * 64 + 32 + ro) * DIM + 32 + l31], C11[r]);
        }
    }
}

// ---------------------------------------------------------------------------
// final (slab) v4: csum merged, P-generic (512 or 1024 slabs).
// ---------------------------------------------------------------------------
__global__ __launch_bounds__(512)
void final_slab_kernel(const unsigned int* __restrict__ slab,
                       const float* __restrict__ cnt_slab,
                       const float* __restrict__ centers,
                       float* __restrict__ out, int P) {
    __shared__ float s0b[8][64], s1b[8][64];
    __shared__ float cfin[2];
    const int tid = threadIdx.x;
    const int q   = tid >> 6;
    const int gl  = tid & 63;
    const int gid = blockIdx.x * 64 + gl;

    float s0 = 0.f, s1 = 0.f;
    for (int b = q; b < P; b += 8) {
        unsigned int u = slab[(size_t)b * 16384 + gid];
        s0 += __builtin_bit_cast(float, u << 16);
        s1 += __builtin_bit_cast(float, u & 0xFFFF0000u);
    }
    s0b[q][gl] = s0; s1b[q][gl] = s1;

    if (tid < 128) {
        const int hf = tid >> 6;
        const int ln = tid & 63;
        const int k  = blockIdx.x * 2 + hf;
        float cp = 0.f;
        for (int b = ln; b < P; b += 64)
            cp += cnt_slab[b * K_CL + k];
#pragma unroll
        for (int off = 1; off < 64; off <<= 1) cp += __shfl_xor(cp, off, 64);
        if (ln == 0) cfin[hf] = cp;
    }
    __syncthreads();

    if (tid < 64) {
        float t0 = 0.f, t1 = 0.f;
#pragma unroll
        for (int j = 0; j < 8; ++j) { t0 += s0b[j][tid]; t1 += s1b[j][tid]; }
        const int g = blockIdx.x * 64 + tid;
        const int k = g >> 5, p = g & 31;
        float c = cfin[(tid >> 5)];
        if (c > 0.f) {
            out[k * DIM + p]      = t0 / c;
            out[k * DIM + 32 + p] = t1 / c;
        } else {
            out[k * DIM + p]      = centers[k * DIM + p];
            out[k * DIM + 32 + p] = centers[k * DIM + 32 + p];
        }
        if (p == 0) out[K_CL * DIM + k] = c;
    }
}

// ---------------------------------------------------------------------------
// final (atomic fallback path)
// ---------------------------------------------------------------------------
__global__ void final_kernel(const float* __restrict__ gsums,
                             const float* __restrict__ gcnt,
                             const float* __restrict__ centers,
                             float* __restrict__ out) {
    int i = blockIdx.x * 256 + threadIdx.x;
    if (i < K_CL * DIM) {
        int k = i >> 6;
        float c = gcnt[k];
        out[i] = (c > 0.f) ? (gsums[i] / c) : centers[i];
    } else if (i < OUTSZ) {
        out[i] = gcnt[i - K_CL * DIM];
    }
}

extern "C" void kernel_launch(void* const* d_in, const int* in_sizes, int n_in,
                              void* d_out, int out_size, void* d_ws, size_t ws_size,
                              hipStream_t stream) {
    const float* x       = (const float*)d_in[0];
    const float* centers = (const float*)d_in[1];

    char* ws = (char*)d_ws;
    unsigned short* chi    = (unsigned short*)(ws);             // 64 KiB (fp16)
    float*          hc2    = (float*)(ws + 131072);             // 2 KiB
    unsigned int*   assign = (unsigned int*)(ws + 133120);      // 2 MiB
    float*          gsums  = (float*)(ws + 2230272);            // 128 KiB
    float*          gcnt   = (float*)(ws + 2361344);            // 2 KiB
    const size_t    fixed  = 2363392;

    // adaptive slab count: P=1024 (4 blocks/CU, 100% occ cap) if ws allows,
    // else proven P=512, else atomic fallback. ws_size is constant ->
    // deterministic choice (graph-safe).
    size_t avail = (ws_size > fixed) ? (ws_size - fixed) : 0;
    int P = 0;
    if (avail >= (size_t)1024 * 65536 + (size_t)1024 * K_CL * 4) P = 1024;
    else if (avail >= (size_t)512 * 65536 + (size_t)512 * K_CL * 4) P = 512;

    prep_kernel<<<K_CL, 64, 0, stream>>>(centers, chi, hc2);
    assign_kernel<<<1024, 512, 0, stream>>>(x, chi, hc2, assign);

    if (P) {
        unsigned int* slab_u32 = (unsigned int*)(ws + fixed);
        float* cnt_slab = (float*)(ws + fixed + (size_t)P * 65536);
        int nsc = N_PTS / (P * 128);   // P=1024 -> 4, P=512 -> 8
        reduce_kernel<1><<<P, 512, 0, stream>>>(x, assign, gsums, gcnt,
                                                slab_u32, cnt_slab, nsc);
        final_slab_kernel<<<256, 512, 0, stream>>>(slab_u32, cnt_slab, centers,
                                                   (float*)d_out, P);
    } else {
        hipMemsetAsync(gsums, 0, (K_CL * DIM + K_CL) * sizeof(float), stream);
        reduce_kernel<0><<<256, 512, 0, stream>>>(x, assign, gsums, gcnt,
                                                  (unsigned int*)ws, gcnt, 16);
        final_kernel<<<(OUTSZ + 255) / 256, 256, 0, stream>>>(
            gsums, gcnt, centers, (float*)d_out);
    }
}

// Round 16
// 110.953 us; speedup vs baseline: 1.2110x; 1.2110x over previous
//
#include <hip/hip_runtime.h>
#include <hip/hip_bf16.h>

typedef __attribute__((ext_vector_type(8)))  short short8;
typedef __attribute__((ext_vector_type(16))) float f32x16;
typedef _Float16 __attribute__((ext_vector_type(8))) half8;

#define DIM   64
#define K_CL  512
#define N_PTS 524288
#define OUTSZ (K_CL * DIM + K_CL)   // 33280

// pack two fp32 -> one u32 of 2x bf16 (RNE) via compiler cvt_pk path
__device__ inline unsigned int pk_bf16(float a, float b) {
    float2 t; t.x = a; t.y = b;
    __hip_bfloat162 h2 = __float22bfloat162_rn(t);
    unsigned int u;
    __builtin_memcpy(&u, &h2, 4);
    return u;
}

// convert float4 -> 4 fp16 (RNE via v_cvt_f16_f32), packed as uint2
__device__ inline uint2 cvt4_f16(const float4& v) {
    unsigned short a = __builtin_bit_cast(unsigned short, (_Float16)v.x);
    unsigned short b = __builtin_bit_cast(unsigned short, (_Float16)v.y);
    unsigned short c = __builtin_bit_cast(unsigned short, (_Float16)v.z);
    unsigned short d = __builtin_bit_cast(unsigned short, (_Float16)v.w);
    uint2 w;
    w.x = (unsigned int)a | ((unsigned int)b << 16);
    w.y = (unsigned int)c | ((unsigned int)d << 16);
    return w;
}

// ---------------------------------------------------------------------------
// prep: one 64-lane block per center. hc2 = 0.5*||c||^2 (shuffle reduce);
// chi = fp16 of NEGATED center (single plane; fp16 1-product assign).
// ---------------------------------------------------------------------------
__global__ __launch_bounds__(64)
void prep_kernel(const float* __restrict__ c,
                 unsigned short* __restrict__ chi,
                 float* __restrict__ hc2) {
    const int k = blockIdx.x, d = threadIdx.x;
    float v = c[k * DIM + d];
    float s = v * v;
#pragma unroll
    for (int off = 1; off < 64; off <<= 1) s += __shfl_xor(s, off, 64);

    chi[k * DIM + d] = __builtin_bit_cast(unsigned short, (_Float16)(-v));
    if (d == 0) hc2[k] = 0.5f * s;
}

// ---------------------------------------------------------------------------
// assign v4 (unchanged): fp16 single-product, 1024 blocks x 512 thr, 16
// tiles; bias as ks=0 MFMA C-in; double-buffered staging; one barrier per
// tile; exact float argmin; u64 atomicMin winner.
// ---------------------------------------------------------------------------
__global__ __launch_bounds__(512, 4)
void assign_kernel(const float* __restrict__ x,
                   const unsigned short* __restrict__ chi_g,
                   const float* __restrict__ hc2g,
                   unsigned int* __restrict__ assign) {
    __shared__ unsigned int lds_x[2][1024];
    __shared__ float lds_bias[512];
    __shared__ unsigned long long lds_best[512];

    const int tid  = threadIdx.x;
    const int wave = tid >> 6;
    const int lane = tid & 63;
    const int l31  = lane & 31;
    const int h    = lane >> 5;

    lds_best[tid] = ~0ull;
    {
        int w = tid >> 6, ct = (tid >> 5) & 1, hh = (tid >> 4) & 1, r = tid & 15;
        lds_bias[tid] = hc2g[w * 64 + ct * 32 + (r & 3) + 8 * (r >> 2) + 4 * hh];
    }

    half8 cH[2][4];
#pragma unroll
    for (int ct = 0; ct < 2; ++ct) {
        int row = wave * 64 + ct * 32 + l31;
#pragma unroll
        for (int ks = 0; ks < 4; ++ks) {
            size_t off = (size_t)row * DIM + ks * 16 + h * 8;
            cH[ct][ks] = __builtin_bit_cast(half8, *(const short8*)(chi_g + off));
        }
    }

    const int p_st  = tid >> 4;
    const int dgrp  = tid & 15;
    const int f_st  = dgrp >> 1;
    const int half  = dgrp & 1;
    const int widx  = f_st * 128 + ((p_st ^ (f_st & 7)) << 2) + half * 2;

    const size_t xbase = (size_t)blockIdx.x * 32768 + tid * 4;

#define STAGE(buf, v4)                                                        \
    {                                                                         \
        uint2 w2 = cvt4_f16(v4);                                              \
        *(uint2*)&lds_x[buf][widx] = w2;                                      \
    }

    float4 pf = *(const float4*)(x + xbase);
    STAGE(0, pf)
    pf = *(const float4*)(x + xbase + 2048);
    __syncthreads();

    f32x16 bias0, bias1;
    {
        const float4* b0 = (const float4*)&lds_bias[wave * 64 + h * 16];
        const float4* b1 = (const float4*)&lds_bias[wave * 64 + 32 + h * 16];
#pragma unroll
        for (int g = 0; g < 4; ++g) {
            float4 a = b0[g], bb = b1[g];
            bias0[4*g+0] = a.x;  bias0[4*g+1] = a.y;  bias0[4*g+2] = a.z;  bias0[4*g+3] = a.w;
            bias1[4*g+0] = bb.x; bias1[4*g+1] = bb.y; bias1[4*g+2] = bb.z; bias1[4*g+3] = bb.w;
        }
    }

    const unsigned int base_id = wave * 64 + 4 * h;

    for (int t = 0; t < 16; ++t) {
        const int b = t & 1;
        if (t < 15) STAGE(b ^ 1, pf)
        if (t < 14) pf = *(const float4*)(x + xbase + (size_t)(t + 2) * 2048);

        f32x16 acc0, acc1;
        {
            const int ridx = h * 128 + ((l31 ^ (h & 7)) << 2);
            half8 xh = __builtin_bit_cast(half8, *(const short8*)&lds_x[b][ridx]);
            acc0 = __builtin_amdgcn_mfma_f32_32x32x16_f16(cH[0][0], xh, bias0, 0, 0, 0);
            acc1 = __builtin_amdgcn_mfma_f32_32x32x16_f16(cH[1][0], xh, bias1, 0, 0, 0);
        }
#pragma unroll
        for (int ks = 1; ks < 4; ++ks) {
            const int f = ks * 2 + h;
            const int ridx = f * 128 + ((l31 ^ (f & 7)) << 2);
            half8 xh = __builtin_bit_cast(half8, *(const short8*)&lds_x[b][ridx]);
            acc0 = __builtin_amdgcn_mfma_f32_32x32x16_f16(cH[0][ks], xh, acc0, 0, 0, 0);
            acc1 = __builtin_amdgcn_mfma_f32_32x32x16_f16(cH[1][ks], xh, acc1, 0, 0, 0);
        }

        float bv = acc0[0];
        unsigned int boff = 0;
#pragma unroll
        for (int r = 1; r < 16; ++r) {
            unsigned int off = (r & 3) + 8 * (r >> 2);
            if (acc0[r] < bv) { bv = acc0[r]; boff = off; }
        }
#pragma unroll
        for (int r = 0; r < 16; ++r) {
            unsigned int off = 32 + (r & 3) + 8 * (r >> 2);
            if (acc1[r] < bv) { bv = acc1[r]; boff = off; }
        }

        unsigned int ub = __builtin_bit_cast(unsigned int, bv);
        ub ^= (unsigned int)(((int)ub) >> 31) | 0x80000000u;
        unsigned long long pk =
            ((unsigned long long)ub << 32) | (unsigned long long)(base_id + boff);
        atomicMin(&lds_best[t * 32 + l31], pk);
        __syncthreads();
    }
#undef STAGE

    assign[blockIdx.x * 512 + tid] = (unsigned int)(lds_best[tid] & 0xFFFFFFFFu);
}

// ---------------------------------------------------------------------------
// reduce v6 (kept): one-hot MFMA, bf16-hi B operand; single barrier per
// superchunk (reads buf[b] / writes buf[b^1] disjoint between barriers).
// Grid REVERTED to P=512, nsc=8 (round-15's P=1024 doubled slab traffic and
// per-block fixed costs: +23 us).
// ---------------------------------------------------------------------------
template <int SLAB>
__global__ __launch_bounds__(512)
void reduce_kernel(const float* __restrict__ x,
                   const unsigned int* __restrict__ assign,
                   float* __restrict__ gsums, float* __restrict__ gcnt,
                   unsigned int* __restrict__ slab_u32,
                   float* __restrict__ cnt_slab, int nsc) {
    __shared__ unsigned short lds_h[2][64][128];
    __shared__ unsigned int   lds_a[2][128];
    __shared__ float          lds_cnt[K_CL];

    const int tid  = threadIdx.x;
    const int wave = tid >> 6;
    const int lane = tid & 63;
    const int l31  = lane & 31;
    const int h    = lane >> 5;
    const int d    = lane;
    const int pg   = wave;

    lds_cnt[tid] = 0.f;

    const size_t pbase = (size_t)blockIdx.x * (size_t)(nsc * 128);

    float f[16];
    {
        const float* xp = x + (pbase + pg * 16) * DIM + d;
#pragma unroll
        for (int i = 0; i < 16; ++i) f[i] = xp[(size_t)i * DIM];
    }
    __syncthreads();   // lds_cnt zeros visible

    for (int i = 0; i < (nsc >> 2); ++i)
        atomicAdd(&lds_cnt[assign[pbase + tid + i * 512]], 1.f);

    const int swz = (d & 15) << 3;

#define WRITE_BUF(b)                                                          \
    {                                                                         \
        unsigned int hw[8];                                                   \
        _Pragma("unroll")                                                     \
        for (int q = 0; q < 8; ++q) hw[q] = pk_bf16(f[2*q], f[2*q+1]);        \
        unsigned short* rh = &lds_h[b][d][0];                                 \
        const int j0 = (pg * 16) ^ swz;                                       \
        const int j1 = (pg * 16 + 8) ^ swz;                                   \
        uint4 u;                                                              \
        u.x=hw[0]; u.y=hw[1]; u.z=hw[2]; u.w=hw[3]; *(uint4*)&rh[j0] = u;     \
        u.x=hw[4]; u.y=hw[5]; u.z=hw[6]; u.w=hw[7]; *(uint4*)&rh[j1] = u;     \
    }

    WRITE_BUF(0)
    if (tid < 32) {
        uint4 av = *(const uint4*)(assign + pbase + tid * 4);
        *(uint4*)&lds_a[0][tid * 4] = av;
    }
    __syncthreads();

    const unsigned int row0 = wave * 64 + l31;
    const unsigned int row1 = row0 + 32;
    f32x16 C00 = {}, C01 = {}, C10 = {}, C11 = {};

    for (int sc = 0; sc < nsc; ++sc) {
        const int b = sc & 1;
        if (sc < nsc - 1) {   // issue next superchunk's loads under compute
            const float* xp = x + (pbase + (size_t)(sc + 1) * 128 + pg * 16) * DIM + d;
#pragma unroll
            for (int i = 0; i < 16; ++i) f[i] = xp[(size_t)i * DIM];
        }

#pragma unroll
        for (int c = 0; c < 8; ++c) {
            const unsigned int* ap = &lds_a[b][c * 16 + 8 * h];
            uint4 aA = *(const uint4*)ap;
            uint4 aB = *(const uint4*)(ap + 4);
            unsigned int a[8] = {aA.x, aA.y, aA.z, aA.w, aB.x, aB.y, aB.z, aB.w};
            unsigned int i0[4], i1[4];
#pragma unroll
            for (int q = 0; q < 4; ++q) {
                i0[q] = (a[2*q]==row0 ? 0x3F80u : 0u) | (a[2*q+1]==row0 ? 0x3F800000u : 0u);
                i1[q] = (a[2*q]==row1 ? 0x3F80u : 0u) | (a[2*q+1]==row1 ? 0x3F800000u : 0u);
            }
            uint4 u0; u0.x=i0[0]; u0.y=i0[1]; u0.z=i0[2]; u0.w=i0[3];
            uint4 u1; u1.x=i1[0]; u1.y=i1[1]; u1.z=i1[2]; u1.w=i1[3];
            short8 A0 = __builtin_bit_cast(short8, u0);
            short8 A1 = __builtin_bit_cast(short8, u1);

            const int off = (c * 16 + 8 * h) ^ ((l31 & 15) << 3);
            short8 xh0 = *(const short8*)&lds_h[b][l31][off];
            short8 xh1 = *(const short8*)&lds_h[b][l31 + 32][off];

            C00 = __builtin_amdgcn_mfma_f32_32x32x16_bf16(A0, xh0, C00, 0, 0, 0);
            C01 = __builtin_amdgcn_mfma_f32_32x32x16_bf16(A0, xh1, C01, 0, 0, 0);
            C10 = __builtin_amdgcn_mfma_f32_32x32x16_bf16(A1, xh0, C10, 0, 0, 0);
            C11 = __builtin_amdgcn_mfma_f32_32x32x16_bf16(A1, xh1, C11, 0, 0, 0);
        }

        if (sc < nsc - 1) {   // write NEXT buffer (disjoint from reads of b)
            WRITE_BUF(b ^ 1)
            if (tid < 32) {
                uint4 av = *(const uint4*)(assign + pbase + (size_t)(sc + 1) * 128 + tid * 4);
                *(uint4*)&lds_a[b ^ 1][tid * 4] = av;
            }
        }
        __syncthreads();   // single barrier per superchunk
    }
#undef WRITE_BUF

    if (SLAB) {
        cnt_slab[blockIdx.x * K_CL + tid] = lds_cnt[tid];
        unsigned int* myslab = slab_u32 + (size_t)blockIdx.x * 16384;
#pragma unroll
        for (int r = 0; r < 16; ++r) {
            int ro = (r & 3) + 8 * (r >> 2) + 4 * h;
            int k0 = wave * 64 + ro;
            myslab[k0 * 32 + l31]        = pk_bf16(C00[r], C01[r]);
            myslab[(k0 + 32) * 32 + l31] = pk_bf16(C10[r], C11[r]);
        }
    } else {
        atomicAdd(&gcnt[tid], lds_cnt[tid]);
#pragma unroll
        for (int rr = 0; rr < 16; ++rr) {
            int r = (rr + (int)(blockIdx.x & 15)) & 15;
            int ro = (r & 3) + 8 * (r >> 2) + 4 * h;
            atomicAdd(&gsums[(wave * 64 + ro) * DIM + l31],           C00[r]);
            atomicAdd(&gsums[(wave * 64 + ro) * DIM + 32 + l31],      C01[r]);
            atomicAdd(&gsums[(wave * 64 + 32 + ro) * DIM + l31],      C10[r]);
            atomicAdd(&gsums[(wave * 64 + 32 + ro) * DIM + 32 + l31], C11[r]);
        }
    }
}

// ---------------------------------------------------------------------------
// final (slab) v4: csum merged, P-generic.
// ---------------------------------------------------------------------------
__global__ __launch_bounds__(512)
void final_slab_kernel(const unsigned int* __restrict__ slab,
                       const float* __restrict__ cnt_slab,
                       const float* __restrict__ centers,
                       float* __restrict__ out, int P) {
    __shared__ float s0b[8][64], s1b[8][64];
    __shared__ float cfin[2];
    const int tid = threadIdx.x;
    const int q   = tid >> 6;
    const int gl  = tid & 63;
    const int gid = blockIdx.x * 64 + gl;

    float s0 = 0.f, s1 = 0.f;
    for (int b = q; b < P; b += 8) {
        unsigned int u = slab[(size_t)b * 16384 + gid];
        s0 += __builtin_bit_cast(float, u << 16);
        s1 += __builtin_bit_cast(float, u & 0xFFFF0000u);
    }
    s0b[q][gl] = s0; s1b[q][gl] = s1;

    if (tid < 128) {
        const int hf = tid >> 6;
        const int ln = tid & 63;
        const int k  = blockIdx.x * 2 + hf;
        float cp = 0.f;
        for (int b = ln; b < P; b += 64)
            cp += cnt_slab[b * K_CL + k];
#pragma unroll
        for (int off = 1; off < 64; off <<= 1) cp += __shfl_xor(cp, off, 64);
        if (ln == 0) cfin[hf] = cp;
    }
    __syncthreads();

    if (tid < 64) {
        float t0 = 0.f, t1 = 0.f;
#pragma unroll
        for (int j = 0; j < 8; ++j) { t0 += s0b[j][tid]; t1 += s1b[j][tid]; }
        const int g = blockIdx.x * 64 + tid;
        const int k = g >> 5, p = g & 31;
        float c = cfin[(tid >> 5)];
        if (c > 0.f) {
            out[k * DIM + p]      = t0 / c;
            out[k * DIM + 32 + p] = t1 / c;
        } else {
            out[k * DIM + p]      = centers[k * DIM + p];
            out[k * DIM + 32 + p] = centers[k * DIM + 32 + p];
        }
        if (p == 0) out[K_CL * DIM + k] = c;
    }
}

// ---------------------------------------------------------------------------
// final (atomic fallback path)
// ---------------------------------------------------------------------------
__global__ void final_kernel(const float* __restrict__ gsums,
                             const float* __restrict__ gcnt,
                             const float* __restrict__ centers,
                             float* __restrict__ out) {
    int i = blockIdx.x * 256 + threadIdx.x;
    if (i < K_CL * DIM) {
        int k = i >> 6;
        float c = gcnt[k];
        out[i] = (c > 0.f) ? (gsums[i] / c) : centers[i];
    } else if (i < OUTSZ) {
        out[i] = gcnt[i - K_CL * DIM];
    }
}

extern "C" void kernel_launch(void* const* d_in, const int* in_sizes, int n_in,
                              void* d_out, int out_size, void* d_ws, size_t ws_size,
                              hipStream_t stream) {
    const float* x       = (const float*)d_in[0];
    const float* centers = (const float*)d_in[1];

    char* ws = (char*)d_ws;
    unsigned short* chi    = (unsigned short*)(ws);             // 64 KiB (fp16)
    float*          hc2    = (float*)(ws + 131072);             // 2 KiB
    unsigned int*   assign = (unsigned int*)(ws + 133120);      // 2 MiB
    float*          gsums  = (float*)(ws + 2230272);            // 128 KiB
    float*          gcnt   = (float*)(ws + 2361344);            // 2 KiB
    const size_t    fixed  = 2363392;

    // P = 512 (proven optimum; 1024 doubled slab traffic and per-block
    // fixed costs -> +23 us in round 15). ws_size constant -> graph-safe.
    size_t avail = (ws_size > fixed) ? (ws_size - fixed) : 0;
    int P = (avail >= (size_t)512 * 65536 + (size_t)512 * K_CL * 4) ? 512 : 0;

    prep_kernel<<<K_CL, 64, 0, stream>>>(centers, chi, hc2);
    assign_kernel<<<1024, 512, 0, stream>>>(x, chi, hc2, assign);

    if (P) {
        unsigned int* slab_u32 = (unsigned int*)(ws + fixed);
        float* cnt_slab = (float*)(ws + fixed + (size_t)P * 65536);
        reduce_kernel<1><<<P, 512, 0, stream>>>(x, assign, gsums, gcnt,
                                                slab_u32, cnt_slab, 8);
        final_slab_kernel<<<256, 512, 0, stream>>>(slab_u32, cnt_slab, centers,
                                                   (float*)d_out, P);
    } else {
        hipMemsetAsync(gsums, 0, (K_CL * DIM + K_CL) * sizeof(float), stream);
        reduce_kernel<0><<<256, 512, 0, stream>>>(x, assign, gsums, gcnt,
                                                  (unsigned int*)ws, gcnt, 16);
        final_kernel<<<(OUTSZ + 255) / 256, 256, 0, stream>>>(
            gsums, gcnt, centers, (float*)d_out);
    }
}

// Round 17
// 107.863 us; speedup vs baseline: 1.2457x; 1.0286x over previous
//
#include <hip/hip_runtime.h>
#include <hip/hip_bf16.h>

typedef __attribute__((ext_vector_type(8)))  short short8;
typedef __attribute__((ext_vector_type(16))) float f32x16;
typedef _Float16 __attribute__((ext_vector_type(8))) half8;

#define DIM   64
#define K_CL  512
#define N_PTS 524288
#define OUTSZ (K_CL * DIM + K_CL)   // 33280

// pack two fp32 -> one u32 of 2x bf16 (RNE) via compiler cvt_pk path
__device__ inline unsigned int pk_bf16(float a, float b) {
    float2 t; t.x = a; t.y = b;
    __hip_bfloat162 h2 = __float22bfloat162_rn(t);
    unsigned int u;
    __builtin_memcpy(&u, &h2, 4);
    return u;
}

// convert float4 -> 4 fp16 (RNE via v_cvt_f16_f32), packed as uint2
__device__ inline uint2 cvt4_f16(const float4& v) {
    unsigned short a = __builtin_bit_cast(unsigned short, (_Float16)v.x);
    unsigned short b = __builtin_bit_cast(unsigned short, (_Float16)v.y);
    unsigned short c = __builtin_bit_cast(unsigned short, (_Float16)v.z);
    unsigned short d = __builtin_bit_cast(unsigned short, (_Float16)v.w);
    uint2 w;
    w.x = (unsigned int)a | ((unsigned int)b << 16);
    w.y = (unsigned int)c | ((unsigned int)d << 16);
    return w;
}

// ---------------------------------------------------------------------------
// prep: one 64-lane block per center. hc2 = 0.5*||c||^2 (shuffle reduce);
// chi = fp16 of NEGATED center (single plane; fp16 1-product assign).
// ---------------------------------------------------------------------------
__global__ __launch_bounds__(64)
void prep_kernel(const float* __restrict__ c,
                 unsigned short* __restrict__ chi,
                 float* __restrict__ hc2) {
    const int k = blockIdx.x, d = threadIdx.x;
    float v = c[k * DIM + d];
    float s = v * v;
#pragma unroll
    for (int off = 1; off < 64; off <<= 1) s += __shfl_xor(s, off, 64);

    chi[k * DIM + d] = __builtin_bit_cast(unsigned short, (_Float16)(-v));
    if (d == 0) hc2[k] = 0.5f * s;
}

// ---------------------------------------------------------------------------
// assign v5: fp16 single-product, 1024 blocks x 512 thr, 16 tiles; bias as
// ks=0 MFMA C-in; double-buffered staging; one barrier per tile; u64
// atomicMin winner. CHANGED: argmin via h-half pairing (fminf + offset
// select) then a 16-wide (value,offset) tree: ~93 VALU vs ~141. Identical
// result except on exact float ties (measure-zero for continuous data).
// ---------------------------------------------------------------------------
__global__ __launch_bounds__(512, 4)
void assign_kernel(const float* __restrict__ x,
                   const unsigned short* __restrict__ chi_g,
                   const float* __restrict__ hc2g,
                   unsigned int* __restrict__ assign) {
    __shared__ unsigned int lds_x[2][1024];
    __shared__ float lds_bias[512];
    __shared__ unsigned long long lds_best[512];

    const int tid  = threadIdx.x;
    const int wave = tid >> 6;
    const int lane = tid & 63;
    const int l31  = lane & 31;
    const int h    = lane >> 5;

    lds_best[tid] = ~0ull;
    {
        int w = tid >> 6, ct = (tid >> 5) & 1, hh = (tid >> 4) & 1, r = tid & 15;
        lds_bias[tid] = hc2g[w * 64 + ct * 32 + (r & 3) + 8 * (r >> 2) + 4 * hh];
    }

    half8 cH[2][4];
#pragma unroll
    for (int ct = 0; ct < 2; ++ct) {
        int row = wave * 64 + ct * 32 + l31;
#pragma unroll
        for (int ks = 0; ks < 4; ++ks) {
            size_t off = (size_t)row * DIM + ks * 16 + h * 8;
            cH[ct][ks] = __builtin_bit_cast(half8, *(const short8*)(chi_g + off));
        }
    }

    const int p_st  = tid >> 4;
    const int dgrp  = tid & 15;
    const int f_st  = dgrp >> 1;
    const int half  = dgrp & 1;
    const int widx  = f_st * 128 + ((p_st ^ (f_st & 7)) << 2) + half * 2;

    const size_t xbase = (size_t)blockIdx.x * 32768 + tid * 4;

#define STAGE(buf, v4)                                                        \
    {                                                                         \
        uint2 w2 = cvt4_f16(v4);                                              \
        *(uint2*)&lds_x[buf][widx] = w2;                                      \
    }

    float4 pf = *(const float4*)(x + xbase);
    STAGE(0, pf)
    pf = *(const float4*)(x + xbase + 2048);
    __syncthreads();

    f32x16 bias0, bias1;
    {
        const float4* b0 = (const float4*)&lds_bias[wave * 64 + h * 16];
        const float4* b1 = (const float4*)&lds_bias[wave * 64 + 32 + h * 16];
#pragma unroll
        for (int g = 0; g < 4; ++g) {
            float4 a = b0[g], bb = b1[g];
            bias0[4*g+0] = a.x;  bias0[4*g+1] = a.y;  bias0[4*g+2] = a.z;  bias0[4*g+3] = a.w;
            bias1[4*g+0] = bb.x; bias1[4*g+1] = bb.y; bias1[4*g+2] = bb.z; bias1[4*g+3] = bb.w;
        }
    }

    const unsigned int base_id = wave * 64 + 4 * h;

    for (int t = 0; t < 16; ++t) {
        const int b = t & 1;
        if (t < 15) STAGE(b ^ 1, pf)
        if (t < 14) pf = *(const float4*)(x + xbase + (size_t)(t + 2) * 2048);

        f32x16 acc0, acc1;
        {
            const int ridx = h * 128 + ((l31 ^ (h & 7)) << 2);
            half8 xh = __builtin_bit_cast(half8, *(const short8*)&lds_x[b][ridx]);
            acc0 = __builtin_amdgcn_mfma_f32_32x32x16_f16(cH[0][0], xh, bias0, 0, 0, 0);
            acc1 = __builtin_amdgcn_mfma_f32_32x32x16_f16(cH[1][0], xh, bias1, 0, 0, 0);
        }
#pragma unroll
        for (int ks = 1; ks < 4; ++ks) {
            const int f = ks * 2 + h;
            const int ridx = f * 128 + ((l31 ^ (f & 7)) << 2);
            half8 xh = __builtin_bit_cast(half8, *(const short8*)&lds_x[b][ridx]);
            acc0 = __builtin_amdgcn_mfma_f32_32x32x16_f16(cH[0][ks], xh, acc0, 0, 0, 0);
            acc1 = __builtin_amdgcn_mfma_f32_32x32x16_f16(cH[1][ks], xh, acc1, 0, 0, 0);
        }

        // argmin: pair h-halves (16x fminf + offset select), then 16-wide
        // (value, offset) tree. ~93 VALU vs ~141 for the flat scan.
        float        pv[16];
        unsigned int po[16];
#pragma unroll
        for (int r = 0; r < 16; ++r) {
            unsigned int off = (r & 3) + 8 * (r >> 2);
            bool t1 = acc1[r] < acc0[r];         // tie -> keep acc0 (lower id)
            pv[r] = fminf(acc0[r], acc1[r]);
            po[r] = t1 ? (off + 32u) : off;
        }
#pragma unroll
        for (int s = 8; s > 0; s >>= 1)
#pragma unroll
            for (int i = 0; i < s; ++i)
                if (pv[i + s] < pv[i]) { pv[i] = pv[i + s]; po[i] = po[i + s]; }

        unsigned int ub = __builtin_bit_cast(unsigned int, pv[0]);
        ub ^= (unsigned int)(((int)ub) >> 31) | 0x80000000u;
        unsigned long long pk =
            ((unsigned long long)ub << 32) | (unsigned long long)(base_id + po[0]);
        atomicMin(&lds_best[t * 32 + l31], pk);
        __syncthreads();
    }
#undef STAGE

    assign[blockIdx.x * 512 + tid] = (unsigned int)(lds_best[tid] & 0xFFFFFFFFu);
}

// ---------------------------------------------------------------------------
// reduce v6 (unchanged): one-hot MFMA, bf16-hi B operand; single barrier per
// superchunk; P=512, nsc=8; slab or atomic flush.
// ---------------------------------------------------------------------------
template <int SLAB>
__global__ __launch_bounds__(512)
void reduce_kernel(const float* __restrict__ x,
                   const unsigned int* __restrict__ assign,
                   float* __restrict__ gsums, float* __restrict__ gcnt,
                   unsigned int* __restrict__ slab_u32,
                   float* __restrict__ cnt_slab, int nsc) {
    __shared__ unsigned short lds_h[2][64][128];
    __shared__ unsigned int   lds_a[2][128];
    __shared__ float          lds_cnt[K_CL];

    const int tid  = threadIdx.x;
    const int wave = tid >> 6;
    const int lane = tid & 63;
    const int l31  = lane & 31;
    const int h    = lane >> 5;
    const int d    = lane;
    const int pg   = wave;

    lds_cnt[tid] = 0.f;

    const size_t pbase = (size_t)blockIdx.x * (size_t)(nsc * 128);

    float f[16];
    {
        const float* xp = x + (pbase + pg * 16) * DIM + d;
#pragma unroll
        for (int i = 0; i < 16; ++i) f[i] = xp[(size_t)i * DIM];
    }
    __syncthreads();   // lds_cnt zeros visible

    for (int i = 0; i < (nsc >> 2); ++i)
        atomicAdd(&lds_cnt[assign[pbase + tid + i * 512]], 1.f);

    const int swz = (d & 15) << 3;

#define WRITE_BUF(b)                                                          \
    {                                                                         \
        unsigned int hw[8];                                                   \
        _Pragma("unroll")                                                     \
        for (int q = 0; q < 8; ++q) hw[q] = pk_bf16(f[2*q], f[2*q+1]);        \
        unsigned short* rh = &lds_h[b][d][0];                                 \
        const int j0 = (pg * 16) ^ swz;                                       \
        const int j1 = (pg * 16 + 8) ^ swz;                                   \
        uint4 u;                                                              \
        u.x=hw[0]; u.y=hw[1]; u.z=hw[2]; u.w=hw[3]; *(uint4*)&rh[j0] = u;     \
        u.x=hw[4]; u.y=hw[5]; u.z=hw[6]; u.w=hw[7]; *(uint4*)&rh[j1] = u;     \
    }

    WRITE_BUF(0)
    if (tid < 32) {
        uint4 av = *(const uint4*)(assign + pbase + tid * 4);
        *(uint4*)&lds_a[0][tid * 4] = av;
    }
    __syncthreads();

    const unsigned int row0 = wave * 64 + l31;
    const unsigned int row1 = row0 + 32;
    f32x16 C00 = {}, C01 = {}, C10 = {}, C11 = {};

    for (int sc = 0; sc < nsc; ++sc) {
        const int b = sc & 1;
        if (sc < nsc - 1) {
            const float* xp = x + (pbase + (size_t)(sc + 1) * 128 + pg * 16) * DIM + d;
#pragma unroll
            for (int i = 0; i < 16; ++i) f[i] = xp[(size_t)i * DIM];
        }

#pragma unroll
        for (int c = 0; c < 8; ++c) {
            const unsigned int* ap = &lds_a[b][c * 16 + 8 * h];
            uint4 aA = *(const uint4*)ap;
            uint4 aB = *(const uint4*)(ap + 4);
            unsigned int a[8] = {aA.x, aA.y, aA.z, aA.w, aB.x, aB.y, aB.z, aB.w};
            unsigned int i0[4], i1[4];
#pragma unroll
            for (int q = 0; q < 4; ++q) {
                i0[q] = (a[2*q]==row0 ? 0x3F80u : 0u) | (a[2*q+1]==row0 ? 0x3F800000u : 0u);
                i1[q] = (a[2*q]==row1 ? 0x3F80u : 0u) | (a[2*q+1]==row1 ? 0x3F800000u : 0u);
            }
            uint4 u0; u0.x=i0[0]; u0.y=i0[1]; u0.z=i0[2]; u0.w=i0[3];
            uint4 u1; u1.x=i1[0]; u1.y=i1[1]; u1.z=i1[2]; u1.w=i1[3];
            short8 A0 = __builtin_bit_cast(short8, u0);
            short8 A1 = __builtin_bit_cast(short8, u1);

            const int off = (c * 16 + 8 * h) ^ ((l31 & 15) << 3);
            short8 xh0 = *(const short8*)&lds_h[b][l31][off];
            short8 xh1 = *(const short8*)&lds_h[b][l31 + 32][off];

            C00 = __builtin_amdgcn_mfma_f32_32x32x16_bf16(A0, xh0, C00, 0, 0, 0);
            C01 = __builtin_amdgcn_mfma_f32_32x32x16_bf16(A0, xh1, C01, 0, 0, 0);
            C10 = __builtin_amdgcn_mfma_f32_32x32x16_bf16(A1, xh0, C10, 0, 0, 0);
            C11 = __builtin_amdgcn_mfma_f32_32x32x16_bf16(A1, xh1, C11, 0, 0, 0);
        }

        if (sc < nsc - 1) {
            WRITE_BUF(b ^ 1)
            if (tid < 32) {
                uint4 av = *(const uint4*)(assign + pbase + (size_t)(sc + 1) * 128 + tid * 4);
                *(uint4*)&lds_a[b ^ 1][tid * 4] = av;
            }
        }
        __syncthreads();
    }
#undef WRITE_BUF

    if (SLAB) {
        cnt_slab[blockIdx.x * K_CL + tid] = lds_cnt[tid];
        unsigned int* myslab = slab_u32 + (size_t)blockIdx.x * 16384;
#pragma unroll
        for (int r = 0; r < 16; ++r) {
            int ro = (r & 3) + 8 * (r >> 2) + 4 * h;
            int k0 = wave * 64 + ro;
            myslab[k0 * 32 + l31]        = pk_bf16(C00[r], C01[r]);
            myslab[(k0 + 32) * 32 + l31] = pk_bf16(C10[r], C11[r]);
        }
    } else {
        atomicAdd(&gcnt[tid], lds_cnt[tid]);
#pragma unroll
        for (int rr = 0; rr < 16; ++rr) {
            int r = (rr + (int)(blockIdx.x & 15)) & 15;
            int ro = (r & 3) + 8 * (r >> 2) + 4 * h;
            atomicAdd(&gsums[(wave * 64 + ro) * DIM + l31],           C00[r]);
            atomicAdd(&gsums[(wave * 64 + ro) * DIM + 32 + l31],      C01[r]);
            atomicAdd(&gsums[(wave * 64 + 32 + ro) * DIM + l31],      C10[r]);
            atomicAdd(&gsums[(wave * 64 + 32 + ro) * DIM + 32 + l31], C11[r]);
        }
    }
}

// ---------------------------------------------------------------------------
// final (slab) v5: one block per CLUSTER (512 blocks x 512 thr). Thread
// (q=tid>>5 in [0,16), gl=tid&31): sums 32 slabs (b=q+16j) for gid=k*32+gl.
// Counts: all 512 threads load cnt_slab[b][k] (1 each) + shuffle/LDS reduce.
// Halves the serial sum depth of v4 and doubles block count (2/CU).
// ---------------------------------------------------------------------------
__global__ __launch_bounds__(512)
void final_slab_kernel(const unsigned int* __restrict__ slab,
                       const float* __restrict__ cnt_slab,
                       const float* __restrict__ centers,
                       float* __restrict__ out, int P) {
    __shared__ float s0b[16][32], s1b[16][32];
    __shared__ float cpart[8];
    const int tid = threadIdx.x;
    const int q   = tid >> 5;          // 0..15
    const int gl  = tid & 31;          // dim p
    const int k   = blockIdx.x;        // cluster
    const int gid = k * 32 + gl;

    float s0 = 0.f, s1 = 0.f;
    for (int b = q; b < P; b += 16) {
        unsigned int u = slab[(size_t)b * 16384 + gid];
        s0 += __builtin_bit_cast(float, u << 16);
        s1 += __builtin_bit_cast(float, u & 0xFFFF0000u);
    }
    s0b[q][gl] = s0; s1b[q][gl] = s1;

    // counts: thread b=tid loads cnt_slab[b][k]; wave shuffle-reduce
    {
        float cp = (tid < P) ? cnt_slab[(size_t)tid * K_CL + k] : 0.f;
#pragma unroll
        for (int off = 1; off < 64; off <<= 1) cp += __shfl_xor(cp, off, 64);
        if ((tid & 63) == 0) cpart[tid >> 6] = cp;
    }
    __syncthreads();

    if (tid < 32) {
        float c = 0.f;
#pragma unroll
        for (int j = 0; j < 8; ++j) c += cpart[j];
        float t0 = 0.f, t1 = 0.f;
#pragma unroll
        for (int j = 0; j < 16; ++j) { t0 += s0b[j][tid]; t1 += s1b[j][tid]; }
        if (c > 0.f) {
            out[k * DIM + tid]      = t0 / c;
            out[k * DIM + 32 + tid] = t1 / c;
        } else {
            out[k * DIM + tid]      = centers[k * DIM + tid];
            out[k * DIM + 32 + tid] = centers[k * DIM + 32 + tid];
        }
        if (tid == 0) out[K_CL * DIM + k] = c;
    }
}

// ---------------------------------------------------------------------------
// final (atomic fallback path)
// ---------------------------------------------------------------------------
__global__ void final_kernel(const float* __restrict__ gsums,
                             const float* __restrict__ gcnt,
                             const float* __restrict__ centers,
                             float* __restrict__ out) {
    int i = blockIdx.x * 256 + threadIdx.x;
    if (i < K_CL * DIM) {
        int k = i >> 6;
        float c = gcnt[k];
        out[i] = (c > 0.f) ? (gsums[i] / c) : centers[i];
    } else if (i < OUTSZ) {
        out[i] = gcnt[i - K_CL * DIM];
    }
}

extern "C" void kernel_launch(void* const* d_in, const int* in_sizes, int n_in,
                              void* d_out, int out_size, void* d_ws, size_t ws_size,
                              hipStream_t stream) {
    const float* x       = (const float*)d_in[0];
    const float* centers = (const float*)d_in[1];

    char* ws = (char*)d_ws;
    unsigned short* chi    = (unsigned short*)(ws);             // 64 KiB (fp16)
    float*          hc2    = (float*)(ws + 131072);             // 2 KiB
    unsigned int*   assign = (unsigned int*)(ws + 133120);      // 2 MiB
    float*          gsums  = (float*)(ws + 2230272);            // 128 KiB
    float*          gcnt   = (float*)(ws + 2361344);            // 2 KiB
    const size_t    fixed  = 2363392;

    size_t avail = (ws_size > fixed) ? (ws_size - fixed) : 0;
    int P = (avail >= (size_t)512 * 65536 + (size_t)512 * K_CL * 4) ? 512 : 0;

    prep_kernel<<<K_CL, 64, 0, stream>>>(centers, chi, hc2);
    assign_kernel<<<1024, 512, 0, stream>>>(x, chi, hc2, assign);

    if (P) {
        unsigned int* slab_u32 = (unsigned int*)(ws + fixed);
        float* cnt_slab = (float*)(ws + fixed + (size_t)P * 65536);
        reduce_kernel<1><<<P, 512, 0, stream>>>(x, assign, gsums, gcnt,
                                                slab_u32, cnt_slab, 8);
        final_slab_kernel<<<K_CL, 512, 0, stream>>>(slab_u32, cnt_slab, centers,
                                                    (float*)d_out, P);
    } else {
        hipMemsetAsync(gsums, 0, (K_CL * DIM + K_CL) * sizeof(float), stream);
        reduce_kernel<0><<<256, 512, 0, stream>>>(x, assign, gsums, gcnt,
                                                  (unsigned int*)ws, gcnt, 16);
        final_kernel<<<(OUTSZ + 255) / 256, 256, 0, stream>>>(
            gsums, gcnt, centers, (float*)d_out);
    }
}